// Round 2
// baseline (273.414 us; speedup 1.0000x reference)
//
#include <hip/hip_runtime.h>

// BlockRelLinear: out[p, n*8+o] = sum_i x[p, n*8+i] * blocks[rel[p], n, i, o]
// p in [0,200000), n in [0,16), i,o in [0,8)
// fp32 in/out (per reference dtypes), fp32 accumulate.
//
// Thread layout: 16 threads per point, one per output block n.
//   - x read:  2x float4 (32 B) at x + p*128 + n*8; wave covers 2 KB contiguous
//   - W read:  16x float4, contiguous 256 B of blocks[r][n]; a point's 16 lanes
//              cover the contiguous 4 KB blocks[r] (table = 512 KB, L2-resident)
//   - store:   2x float4 (32 B), coalesced like x

__global__ __launch_bounds__(256) void brl_kernel(
    const float* __restrict__ x,
    const float* __restrict__ w,
    const int* __restrict__ rel,
    float* __restrict__ out,
    int npoints)
{
    int tid = blockIdx.x * 256 + threadIdx.x;
    int p = tid >> 4;          // point
    if (p >= npoints) return;
    int n = tid & 15;          // output block

    int r = rel[p];            // 16 lanes same address -> cache broadcast

    // ---- load x block n: 8 floats = 32 B ----
    const float4* xv = reinterpret_cast<const float4*>(x + (size_t)p * 128 + n * 8);
    float4 x0 = xv[0];
    float4 x1 = xv[1];
    float xf[8] = {x0.x, x0.y, x0.z, x0.w, x1.x, x1.y, x1.z, x1.w};

    // ---- weights: blocks[r][n][i][o], 64 floats contiguous = 256 B ----
    const float4* wv = reinterpret_cast<const float4*>(w + ((size_t)r * 16 + n) * 64);

    float acc[8] = {0.f, 0.f, 0.f, 0.f, 0.f, 0.f, 0.f, 0.f};
    #pragma unroll
    for (int i = 0; i < 8; ++i) {
        float4 w0 = wv[2 * i];
        float4 w1 = wv[2 * i + 1];
        float wf[8] = {w0.x, w0.y, w0.z, w0.w, w1.x, w1.y, w1.z, w1.w};
        #pragma unroll
        for (int o = 0; o < 8; ++o)
            acc[o] = fmaf(xf[i], wf[o], acc[o]);
    }

    // ---- store 8 floats = 32 B ----
    float4* ov = reinterpret_cast<float4*>(out + (size_t)p * 128 + n * 8);
    ov[0] = make_float4(acc[0], acc[1], acc[2], acc[3]);
    ov[1] = make_float4(acc[4], acc[5], acc[6], acc[7]);
}

extern "C" void kernel_launch(void* const* d_in, const int* in_sizes, int n_in,
                              void* d_out, int out_size, void* d_ws, size_t ws_size,
                              hipStream_t stream) {
    const float* x   = (const float*)d_in[0];
    const float* w   = (const float*)d_in[1];
    const int*   rel = (const int*)d_in[2];
    float*       out = (float*)d_out;

    int npoints = in_sizes[2];                 // rel has one entry per point
    int total   = npoints * 16;                // 16 threads per point
    int nblocks = (total + 255) / 256;
    brl_kernel<<<nblocks, 256, 0, stream>>>(x, w, rel, out, npoints);
}

// Round 3
// 239.755 us; speedup vs baseline: 1.1404x; 1.1404x over previous
//
#include <hip/hip_runtime.h>

// BlockRelLinear: out[p, n*8+o] = sum_i x[p, n*8+i] * blocks[rel[p], n, i, o]
// fp32 I/O. Strategy: bucket points by relation (hist/scan/scatter into d_ws),
// then one relation per block-group with that relation's weights held in
// REGISTERS (16 floats/thread) and reused across ~100 points. Removes the
// divergent per-point weight fetches that made round-2 request-rate bound
// (148 us @ 8.6% HBM).

#define SEGS 16  // workgroups per relation in k_main (grid = R*SEGS)

// ---------- pass 1: per-relation histogram (LDS-hierarchical) ----------
__global__ void k_hist(const int* __restrict__ rel, int* __restrict__ counts,
                       int npoints, int R)
{
    extern __shared__ int lds[];
    for (int i = threadIdx.x; i < R; i += blockDim.x) lds[i] = 0;
    __syncthreads();
    int p = blockIdx.x * blockDim.x + threadIdx.x;
    if (p < npoints) atomicAdd(&lds[rel[p]], 1);
    __syncthreads();
    for (int i = threadIdx.x; i < R; i += blockDim.x)
        if (lds[i] > 0) atomicAdd(&counts[i], lds[i]);
}

// ---------- pass 2: exclusive scan over R=128 bins (trivial, serial) ----------
__global__ void k_scan(const int* __restrict__ counts, int* __restrict__ starts,
                       int* __restrict__ cursor, int R)
{
    if (threadIdx.x == 0 && blockIdx.x == 0) {
        int acc = 0;
        for (int i = 0; i < R; ++i) { starts[i] = acc; cursor[i] = acc; acc += counts[i]; }
    }
}

// ---------- pass 3: scatter point ids into relation-sorted perm ----------
// Block-local ranks via LDS atomics, one global atomicAdd per (block, bin).
__global__ void k_scatter(const int* __restrict__ rel, int* __restrict__ cursor,
                          int* __restrict__ perm, int npoints, int R)
{
    extern __shared__ int lds[];
    int* cnt  = lds;
    int* base = lds + R;
    for (int i = threadIdx.x; i < R; i += blockDim.x) cnt[i] = 0;
    __syncthreads();
    int p = blockIdx.x * blockDim.x + threadIdx.x;
    int r = -1, rank = 0;
    if (p < npoints) { r = rel[p]; rank = atomicAdd(&cnt[r], 1); }
    __syncthreads();
    for (int i = threadIdx.x; i < R; i += blockDim.x)
        base[i] = (cnt[i] > 0) ? atomicAdd(&cursor[i], cnt[i]) : 0;
    __syncthreads();
    if (r >= 0) perm[base[r] + rank] = p;
}

// ---------- pass 4: main compute, one relation per SEGS block group ----------
// Thread layout: lane l -> n = l>>2 (output block), c = l&3 (column pair 2c,2c+1).
// Each thread keeps W[r][n][i][2c..2c+1] (16 floats) in registers for the whole
// block; each wave streams points of relation r (stride 4 waves/block).
// x load: 2x dwordx4 per lane (4 lanes share an address -> broadcast, 512 B/point)
// out store: float2 per lane -> 512 B contiguous per point, fully coalesced.
__global__ __launch_bounds__(256) void k_main(
    const float* __restrict__ x, const float* __restrict__ w,
    const int* __restrict__ starts, const int* __restrict__ counts,
    const int* __restrict__ perm, float* __restrict__ out)
{
    int r   = blockIdx.x >> 4;       // SEGS == 16
    int seg = blockIdx.x & (SEGS - 1);
    int start = starts[r], cnt = counts[r];
    int lo = start + (cnt * seg) / SEGS;
    int hi = start + (cnt * (seg + 1)) / SEGS;

    int lane = threadIdx.x & 63;
    int wv   = threadIdx.x >> 6;     // 0..3 waves per block
    int n = lane >> 2, c = lane & 3;

    // weights for this thread's (n, column-pair): 16 floats, L2-hot, amortized
    const float* wb = w + ((size_t)r * 16 + n) * 64 + 2 * c;
    float w0[8], w1[8];
    #pragma unroll
    for (int i = 0; i < 8; ++i) {
        float2 t = *reinterpret_cast<const float2*>(wb + i * 8);
        w0[i] = t.x; w1[i] = t.y;
    }

    const int xoff = n * 8;
    const int ooff = n * 8 + 2 * c;

    int idx = lo + wv;
    int p_cur = 0; float4 xa, xb;
    if (idx < hi) {
        p_cur = __builtin_amdgcn_readfirstlane(perm[idx]);
        const float4* xv = reinterpret_cast<const float4*>(x + (size_t)p_cur * 128 + xoff);
        xa = xv[0]; xb = xv[1];
    }
    while (idx < hi) {
        // ---- prefetch next point (1-deep software pipeline) ----
        int nidx = idx + 4;
        int p_nxt = 0; float4 ya, yb;
        bool have = nidx < hi;
        if (have) {
            p_nxt = __builtin_amdgcn_readfirstlane(perm[nidx]);
            const float4* yv = reinterpret_cast<const float4*>(x + (size_t)p_nxt * 128 + xoff);
            ya = yv[0]; yb = yv[1];
        }
        // ---- compute current point (same i-order as round 2: absmax was 0.0) ----
        float a0 = 0.f, a1 = 0.f;
        a0 = fmaf(xa.x, w0[0], a0); a1 = fmaf(xa.x, w1[0], a1);
        a0 = fmaf(xa.y, w0[1], a0); a1 = fmaf(xa.y, w1[1], a1);
        a0 = fmaf(xa.z, w0[2], a0); a1 = fmaf(xa.z, w1[2], a1);
        a0 = fmaf(xa.w, w0[3], a0); a1 = fmaf(xa.w, w1[3], a1);
        a0 = fmaf(xb.x, w0[4], a0); a1 = fmaf(xb.x, w1[4], a1);
        a0 = fmaf(xb.y, w0[5], a0); a1 = fmaf(xb.y, w1[5], a1);
        a0 = fmaf(xb.z, w0[6], a0); a1 = fmaf(xb.z, w1[6], a1);
        a0 = fmaf(xb.w, w0[7], a0); a1 = fmaf(xb.w, w1[7], a1);
        *reinterpret_cast<float2*>(out + (size_t)p_cur * 128 + ooff) = make_float2(a0, a1);

        idx = nidx;
        if (have) { p_cur = p_nxt; xa = ya; xb = yb; }
    }
}

// ---------- fallback (round-2 kernel) if workspace is too small ----------
__global__ __launch_bounds__(256) void brl_kernel(
    const float* __restrict__ x, const float* __restrict__ w,
    const int* __restrict__ rel, float* __restrict__ out, int npoints)
{
    int tid = blockIdx.x * 256 + threadIdx.x;
    int p = tid >> 4;
    if (p >= npoints) return;
    int n = tid & 15;
    int r = rel[p];
    const float4* xv = reinterpret_cast<const float4*>(x + (size_t)p * 128 + n * 8);
    float4 x0 = xv[0], x1 = xv[1];
    float xf[8] = {x0.x, x0.y, x0.z, x0.w, x1.x, x1.y, x1.z, x1.w};
    const float4* wv = reinterpret_cast<const float4*>(w + ((size_t)r * 16 + n) * 64);
    float acc[8] = {0.f,0.f,0.f,0.f,0.f,0.f,0.f,0.f};
    #pragma unroll
    for (int i = 0; i < 8; ++i) {
        float4 w0 = wv[2*i], w1 = wv[2*i+1];
        float wf[8] = {w0.x,w0.y,w0.z,w0.w,w1.x,w1.y,w1.z,w1.w};
        #pragma unroll
        for (int o = 0; o < 8; ++o) acc[o] = fmaf(xf[i], wf[o], acc[o]);
    }
    float4* ov = reinterpret_cast<float4*>(out + (size_t)p * 128 + n * 8);
    ov[0] = make_float4(acc[0], acc[1], acc[2], acc[3]);
    ov[1] = make_float4(acc[4], acc[5], acc[6], acc[7]);
}

extern "C" void kernel_launch(void* const* d_in, const int* in_sizes, int n_in,
                              void* d_out, int out_size, void* d_ws, size_t ws_size,
                              hipStream_t stream) {
    const float* x   = (const float*)d_in[0];
    const float* w   = (const float*)d_in[1];
    const int*   rel = (const int*)d_in[2];
    float*       out = (float*)d_out;

    int npoints = in_sizes[2];
    int R = in_sizes[1] / 1024;          // R * nb(16) * ib(8) * ob(8)

    size_t need = (size_t)(3 * R + npoints) * sizeof(int);
    if (R <= 0 || ws_size < need) {
        int total = npoints * 16;
        brl_kernel<<<(total + 255) / 256, 256, 0, stream>>>(x, w, rel, out, npoints);
        return;
    }

    int* counts = (int*)d_ws;
    int* starts = counts + R;
    int* cursor = starts + R;
    int* perm   = cursor + R;

    hipMemsetAsync(d_ws, 0, (size_t)3 * R * sizeof(int), stream);
    int nb = (npoints + 255) / 256;
    k_hist   <<<nb, 256, R * sizeof(int),     stream>>>(rel, counts, npoints, R);
    k_scan   <<<1, 64, 0,                     stream>>>(counts, starts, cursor, R);
    k_scatter<<<nb, 256, 2 * R * sizeof(int), stream>>>(rel, cursor, perm, npoints, R);
    k_main   <<<R * SEGS, 256, 0,             stream>>>(x, w, starts, counts, perm, out);
}

// Round 4
// 212.533 us; speedup vs baseline: 1.2865x; 1.1281x over previous
//
#include <hip/hip_runtime.h>

// BlockRelLinear: out[p, n*8+o] = sum_i x[p, n*8+i] * blocks[rel[p], n, i, o]
// fp32 I/O. Relation-sorted two-phase. Round-4 fixes:
//  - pre-passes: <=128 atomics/address (was ~670/address -> ~168 us of the 240)
//  - k_main: per-wave batched perm load + readlane broadcast + 4-point ping-pong
//    pipeline (8 outstanding dwordx4/wave) to fix latency-boundness (72us @ 27% HBM).

#define SEGS 16
#define NR 128   // relations (guarded in kernel_launch; fallback otherwise)

// ---------- pass 1: histogram, 128 grid-stride blocks ----------
__global__ __launch_bounds__(256) void k_hist(const int* __restrict__ rel,
                                              int* __restrict__ counts, int npoints)
{
    __shared__ int h[NR];
    for (int i = threadIdx.x; i < NR; i += 256) h[i] = 0;
    __syncthreads();
    for (int p = blockIdx.x * 256 + threadIdx.x; p < npoints; p += gridDim.x * 256)
        atomicAdd(&h[rel[p]], 1);
    __syncthreads();
    for (int i = threadIdx.x; i < NR; i += 256)
        if (h[i]) atomicAdd(&counts[i], h[i]);
}

// ---------- pass 2: exclusive scan over NR bins, parallel ----------
__global__ __launch_bounds__(NR) void k_scan(const int* __restrict__ counts,
                                             int* __restrict__ starts,
                                             int* __restrict__ cursor)
{
    __shared__ int buf[NR];
    int t = threadIdx.x;
    int v = counts[t];
    buf[t] = v;
    __syncthreads();
    #pragma unroll
    for (int off = 1; off < NR; off <<= 1) {
        int y = (t >= off) ? buf[t - off] : 0;
        __syncthreads();
        buf[t] += y;
        __syncthreads();
    }
    int excl = buf[t] - v;
    starts[t] = excl;
    cursor[t] = excl;
}

// ---------- pass 3: scatter, 128 blocks, contiguous chunks ----------
__global__ __launch_bounds__(256) void k_scatter(const int* __restrict__ rel,
                                                 int* __restrict__ cursor,
                                                 int* __restrict__ perm, int npoints)
{
    __shared__ int cnt[NR], base[NR], rk[NR];
    int chunk = (npoints + gridDim.x - 1) / gridDim.x;
    int lo = blockIdx.x * chunk;
    int hi = min(lo + chunk, npoints);
    for (int i = threadIdx.x; i < NR; i += 256) { cnt[i] = 0; rk[i] = 0; }
    __syncthreads();
    for (int p = lo + threadIdx.x; p < hi; p += 256) atomicAdd(&cnt[rel[p]], 1);
    __syncthreads();
    for (int i = threadIdx.x; i < NR; i += 256)
        base[i] = cnt[i] ? atomicAdd(&cursor[i], cnt[i]) : 0;
    __syncthreads();
    for (int p = lo + threadIdx.x; p < hi; p += 256) {
        int r = rel[p];
        int k = atomicAdd(&rk[r], 1);
        perm[base[r] + k] = p;
    }
}

// ---------- pass 4: main compute ----------
// lane l -> n = l>>2 (output block), c = l&3 (column pair). Weights in registers.
// Each wave owns a contiguous quarter of its segment's perm slice; loads up to
// 64 perm entries in ONE vector load, broadcasts via readlane (no per-point
// perm->x latency chain), and pipelines 4-point groups ping-pong.
__global__ __launch_bounds__(256) void k_main(
    const float* __restrict__ x, const float* __restrict__ w,
    const int* __restrict__ starts, const int* __restrict__ counts,
    const int* __restrict__ perm, float* __restrict__ out)
{
    int r   = blockIdx.x >> 4;       // SEGS == 16
    int seg = blockIdx.x & (SEGS - 1);
    int start = starts[r], cnt = counts[r];
    int lo = start + (cnt * seg) / SEGS;
    int hi = start + (cnt * (seg + 1)) / SEGS;
    int scnt = hi - lo;

    int lane = threadIdx.x & 63;
    int wv   = threadIdx.x >> 6;
    int n = lane >> 2, c = lane & 3;

    // this thread's weight columns: W[r][n][i][2c], W[r][n][i][2c+1]
    const float* wb = w + ((size_t)r * 16 + n) * 64 + 2 * c;
    float w0[8], w1[8];
    #pragma unroll
    for (int i = 0; i < 8; ++i) {
        float2 t = *reinterpret_cast<const float2*>(wb + i * 8);
        w0[i] = t.x; w1[i] = t.y;
    }

    int wlo = lo + (scnt * wv) / 4;        // contiguous per-wave range
    int whi = lo + (scnt * (wv + 1)) / 4;
    int nk  = whi - wlo;

    const int xoff = n * 8;
    const int ooff = n * 8 + 2 * c;

    for (int k0 = 0; k0 < nk; k0 += 64) {
        int nbatch = min(64, nk - k0);
        int pidx = (lane < nbatch) ? perm[wlo + k0 + lane] : 0;

        int    P0[4], P1[4];
        float4 X0[4][2], X1[4][2];

        auto loadg = [&](int j0, int P[4], float4 X[4][2]) {
            #pragma unroll
            for (int u = 0; u < 4; ++u) {
                int j = j0 + u;
                if (j < nbatch) {                // wave-uniform branch
                    int p = __builtin_amdgcn_readlane(pidx, j);
                    P[u] = p;
                    const float4* xv = reinterpret_cast<const float4*>(
                        x + (size_t)p * 128 + xoff);
                    X[u][0] = xv[0];
                    X[u][1] = xv[1];
                } else {
                    P[u] = -1;
                }
            }
        };
        auto computeg = [&](const int P[4], const float4 X[4][2]) {
            #pragma unroll
            for (int u = 0; u < 4; ++u) {
                if (P[u] < 0) continue;          // wave-uniform
                float4 xa = X[u][0], xb = X[u][1];
                float a0 = 0.f, a1 = 0.f;        // same i-order as round 2/3 (absmax 0.0)
                a0 = fmaf(xa.x, w0[0], a0); a1 = fmaf(xa.x, w1[0], a1);
                a0 = fmaf(xa.y, w0[1], a0); a1 = fmaf(xa.y, w1[1], a1);
                a0 = fmaf(xa.z, w0[2], a0); a1 = fmaf(xa.z, w1[2], a1);
                a0 = fmaf(xa.w, w0[3], a0); a1 = fmaf(xa.w, w1[3], a1);
                a0 = fmaf(xb.x, w0[4], a0); a1 = fmaf(xb.x, w1[4], a1);
                a0 = fmaf(xb.y, w0[5], a0); a1 = fmaf(xb.y, w1[5], a1);
                a0 = fmaf(xb.z, w0[6], a0); a1 = fmaf(xb.z, w1[6], a1);
                a0 = fmaf(xb.w, w0[7], a0); a1 = fmaf(xb.w, w1[7], a1);
                *reinterpret_cast<float2*>(out + (size_t)P[u] * 128 + ooff) =
                    make_float2(a0, a1);
            }
        };

        loadg(0, P0, X0);
        int j0 = 0;
        while (j0 < nbatch) {
            loadg(j0 + 4, P1, X1);
            computeg(P0, X0);
            j0 += 4;
            if (j0 >= nbatch) break;
            loadg(j0 + 4, P0, X0);
            computeg(P1, X1);
            j0 += 4;
        }
    }
}

// ---------- fallback (round-2 kernel) ----------
__global__ __launch_bounds__(256) void brl_kernel(
    const float* __restrict__ x, const float* __restrict__ w,
    const int* __restrict__ rel, float* __restrict__ out, int npoints)
{
    int tid = blockIdx.x * 256 + threadIdx.x;
    int p = tid >> 4;
    if (p >= npoints) return;
    int n = tid & 15;
    int r = rel[p];
    const float4* xv = reinterpret_cast<const float4*>(x + (size_t)p * 128 + n * 8);
    float4 x0 = xv[0], x1 = xv[1];
    float xf[8] = {x0.x, x0.y, x0.z, x0.w, x1.x, x1.y, x1.z, x1.w};
    const float4* wv = reinterpret_cast<const float4*>(w + ((size_t)r * 16 + n) * 64);
    float acc[8] = {0.f,0.f,0.f,0.f,0.f,0.f,0.f,0.f};
    #pragma unroll
    for (int i = 0; i < 8; ++i) {
        float4 w0 = wv[2*i], w1 = wv[2*i+1];
        float wf[8] = {w0.x,w0.y,w0.z,w0.w,w1.x,w1.y,w1.z,w1.w};
        #pragma unroll
        for (int o = 0; o < 8; ++o) acc[o] = fmaf(xf[i], wf[o], acc[o]);
    }
    float4* ov = reinterpret_cast<float4*>(out + (size_t)p * 128 + n * 8);
    ov[0] = make_float4(acc[0], acc[1], acc[2], acc[3]);
    ov[1] = make_float4(acc[4], acc[5], acc[6], acc[7]);
}

extern "C" void kernel_launch(void* const* d_in, const int* in_sizes, int n_in,
                              void* d_out, int out_size, void* d_ws, size_t ws_size,
                              hipStream_t stream) {
    const float* x   = (const float*)d_in[0];
    const float* w   = (const float*)d_in[1];
    const int*   rel = (const int*)d_in[2];
    float*       out = (float*)d_out;

    int npoints = in_sizes[2];
    int R = in_sizes[1] / 1024;          // R * nb(16) * ib(8) * ob(8)

    size_t need = (size_t)(3 * NR + npoints) * sizeof(int);
    if (R != NR || ws_size < need) {
        int total = npoints * 16;
        brl_kernel<<<(total + 255) / 256, 256, 0, stream>>>(x, w, rel, out, npoints);
        return;
    }

    int* counts = (int*)d_ws;
    int* starts = counts + NR;
    int* cursor = starts + NR;
    int* perm   = cursor + NR;

    hipMemsetAsync(counts, 0, NR * sizeof(int), stream);
    k_hist   <<<128, 256, 0, stream>>>(rel, counts, npoints);
    k_scan   <<<1, NR, 0, stream>>>(counts, starts, cursor);
    k_scatter<<<128, 256, 0, stream>>>(rel, cursor, perm, npoints);
    k_main   <<<NR * SEGS, 256, 0, stream>>>(x, w, starts, counts, perm, out);
}